// Round 8
// baseline (948.777 us; speedup 1.0000x reference)
//
#include <hip/hip_runtime.h>
#include <hip/hip_bf16.h>
#include <math.h>

#define D_DIM   1024
#define P_DIM   128
#define B_ROWS  4096
#define NBANK   8192
#define C_CLS   1000
#define EPS_BN  1e-5f
#define SCALE_S 0.1f
#define MTOT    20480   // 4096 + 8192 + 8192 batched pre_project rows
#define KSPLIT  4       // A@V split-K chunks

typedef __bf16 bf16x8 __attribute__((ext_vector_type(8)));
typedef float  f32x4  __attribute__((ext_vector_type(4)));
typedef __hip_bfloat16 bf;

__device__ __forceinline__ void load_lds16(const void* gp, void* lp) {
    __builtin_amdgcn_global_load_lds(
        (__attribute__((address_space(1))) void*)gp,
        (__attribute__((address_space(3))) void*)lp, 16, 0, 0);
}

// ---------------------------------------------------------------------------
// bf16 MFMA GEMM: C[M,N] = A[M,K] @ B[N,K]^T (row-major bf16), 128x128 tile.
// A row stride = K; B row stride = ldb. kchunks>1 -> split-K via blockIdx.z.
// XCD swizzle: fx*fy must be 8 (round-robin block->XCD heuristic).
// epi: 1 +bias,BN,ReLU -> bf16 | 3 fp32 +bias + addsrc[(gm&(ldc-1))*N+gn] |
//      4 fp32 *exp(*lsp), cols<ldc | 5 bf16 (+bias[n], +biasm[m]) |
//      6 bf16 partial at Cb + z*M*N | 7 bf16 exp(SCALE_S*val) + atomic rowsum
// bf16 epis (1,5,6,7) store via per-wave LDS staging -> dwordx4 coalesced.
// ---------------------------------------------------------------------------
__global__ __launch_bounds__(256)
void gemm_bf16(const bf* __restrict__ A, const bf* __restrict__ B,
               int M, int N, int K, int ldb, int kchunks, int fx, int fy, int epi,
               float* __restrict__ Cf, bf* __restrict__ Cb,
               const float* __restrict__ bias, const float* __restrict__ biasm,
               const float* __restrict__ bng, const float* __restrict__ bnb,
               const float* __restrict__ bnm, const float* __restrict__ bnv,
               const float* __restrict__ addsrc, const float* __restrict__ lsp,
               float* __restrict__ rsum, int ldc)
{
    __shared__ __align__(16) short ldsS[8192];   // 16 KB
    short* lsA = ldsS;          // [128][32]
    short* lsB = ldsS + 4096;   // [128][32]

    const int tid  = threadIdx.x;
    const int wave = tid >> 6;
    const int lane = tid & 63;
    const int wm   = wave >> 1;
    const int wn   = wave & 1;
    const int r16  = lane & 15;
    const int quad = lane >> 4;

    // XCD-aware tile remap
    const int gx = gridDim.x, gy = gridDim.y;
    const int l   = blockIdx.y * gx + blockIdx.x;
    const int xcd = l & 7;
    const int i0  = l >> 3;
    const int sx  = gx / fx, sy = gy / fy;
    const int bx  = (xcd % fx) * sx + (i0 % sx);
    const int by  = (xcd / fx) * sy + (i0 / sx);
    const int bm0 = by * 128;
    const int bn0 = bx * 128;

    const int kper = K / kchunks;
    const int kbeg = blockIdx.z * kper;
    const int niter = kper >> 5;

    // strength-reduced staging pointers: advance by 32 elems (64 B) per iter
    const int seg  = (tid & 3) * 8;   // 16B segment within a 32-elem row
    const int row0 = tid >> 2;        // 0..63
    const bf* gA0 = A + (size_t)(bm0 + row0) * K + kbeg + seg;
    const bf* gA1 = gA0 + (size_t)64 * K;
    const bf* gB0 = B + (size_t)(bn0 + row0) * ldb + kbeg + seg;
    const bf* gB1 = gB0 + (size_t)64 * ldb;
    char* ldsA0 = (char*)lsA + wave * 1024;
    char* ldsA1 = (char*)lsA + 4096 + wave * 1024;
    char* ldsB0 = (char*)lsB + wave * 1024;
    char* ldsB1 = (char*)lsB + 4096 + wave * 1024;
    // fragment read bases (loop-invariant)
    const short* pA = lsA + (wm * 64 + r16) * 32 + quad * 8;
    const short* pB = lsB + (wn * 64 + r16) * 32 + quad * 8;

    f32x4 acc[4][4];
#pragma unroll
    for (int i = 0; i < 4; ++i)
#pragma unroll
        for (int j = 0; j < 4; ++j) acc[i][j] = (f32x4){0.f, 0.f, 0.f, 0.f};

    for (int it = 0; it < niter; ++it) {
        load_lds16(gA0, ldsA0);
        load_lds16(gB0, ldsB0);
        load_lds16(gA1, ldsA1);
        load_lds16(gB1, ldsB1);
        gA0 += 32; gA1 += 32; gB0 += 32; gB1 += 32;
        __syncthreads();

        bf16x8 af[4], bfr[4];
#pragma unroll
        for (int i = 0; i < 4; ++i) af[i] = *(const bf16x8*)(pA + i * 512);
#pragma unroll
        for (int j = 0; j < 4; ++j) bfr[j] = *(const bf16x8*)(pB + j * 512);
#pragma unroll
        for (int i = 0; i < 4; ++i)
#pragma unroll
            for (int j = 0; j < 4; ++j)
                acc[i][j] = __builtin_amdgcn_mfma_f32_16x16x32_bf16(
                    af[i], bfr[j], acc[i][j], 0, 0, 0);
        __syncthreads();
    }
    // after final barrier all LDS fragment reads are complete -> safe to reuse

    if (epi == 3 || epi == 4) {
        const float lsv = (epi == 4) ? expf(*lsp) : 1.0f;
#pragma unroll
        for (int i = 0; i < 4; ++i) {
            const int gmb = bm0 + wm * 64 + i * 16 + quad * 4;
#pragma unroll
            for (int j = 0; j < 4; ++j) {
                const int gn = bn0 + wn * 64 + j * 16 + r16;
#pragma unroll
                for (int r = 0; r < 4; ++r) {
                    const int gm = gmb + r;
                    float val = acc[i][j][r];
                    if (epi == 3) {
                        Cf[(size_t)gm * N + gn] =
                            val + bias[gn] + addsrc[(size_t)(gm & (ldc - 1)) * N + gn];
                    } else {
                        if (gn < ldc) Cf[(size_t)gm * ldc + gn] = val * lsv;
                    }
                }
            }
        }
        return;
    }

    // bf16 LDS-staged store path (epi 1, 5, 6, 7)
    bf* dst = Cb + (epi == 6 ? (size_t)blockIdx.z * M * N : 0);
    bf* my  = (bf*)(ldsS + wave * 2048);   // 4 KB per wave: [32][64] bf16
    float rs[4][4];
#pragma unroll
    for (int i = 0; i < 4; ++i)
#pragma unroll
        for (int r = 0; r < 4; ++r) rs[i][r] = 0.f;

#pragma unroll
    for (int half = 0; half < 2; ++half) {
#pragma unroll
        for (int i2 = 0; i2 < 2; ++i2) {
            const int i = half * 2 + i2;
            const int gmb = bm0 + wm * 64 + i * 16 + quad * 4;
#pragma unroll
            for (int j = 0; j < 4; ++j) {
                const int gn = bn0 + wn * 64 + j * 16 + r16;
#pragma unroll
                for (int r = 0; r < 4; ++r) {
                    float val = acc[i][j][r];
                    if (epi == 1) {
                        val += bias[gn];
                        val = (val - bnm[gn]) * rsqrtf(bnv[gn] + EPS_BN) * bng[gn] + bnb[gn];
                        val = fmaxf(val, 0.f);
                    } else if (epi == 7) {
                        val = __expf(SCALE_S * val);
                        rs[i][r] += val;
                    } else {
                        if (bias)  val += bias[gn];
                        if (biasm) val += biasm[gmb + r];
                    }
                    my[(i2 * 16 + quad * 4 + r) * 64 + j * 16 + r16] =
                        __float2bfloat16(val);
                }
            }
        }
#pragma unroll
        for (int it = 0; it < 4; ++it) {
            const int chunk = it * 64 + lane;
            const int lrow  = chunk >> 3;
            const int lcol  = (chunk & 7) * 8;
            const int grow  = bm0 + wm * 64 + half * 32 + lrow;
            const int gcol  = bn0 + wn * 64 + lcol;
            int4 v = *(const int4*)(my + lrow * 64 + lcol);
            *(int4*)(dst + (size_t)grow * N + gcol) = v;
        }
    }

    if (epi == 7) {
        // reduce each row-partial across the 16 lanes (r16) sharing the row,
        // then one device-scope atomicAdd per row per wave
#pragma unroll
        for (int i = 0; i < 4; ++i)
#pragma unroll
            for (int r = 0; r < 4; ++r) {
                float v = rs[i][r];
                v += __shfl_xor(v, 1, 64);
                v += __shfl_xor(v, 2, 64);
                v += __shfl_xor(v, 4, 64);
                v += __shfl_xor(v, 8, 64);
                if (r16 == 0)
                    atomicAdd(&rsum[bm0 + wm * 64 + i * 16 + quad * 4 + r], v);
            }
    }
}

// zero fp32 buffer
__global__ __launch_bounds__(256)
void zerof(float* __restrict__ p, int n)
{
    int i = blockIdx.x * 256 + threadIdx.x;
    if (i < n) p[i] = 0.f;
}

// sum KSPLIT bf16 partials (stride psz), divide by rowsum[row] -> bf16
__global__ __launch_bounds__(256)
void reduce_parts(const bf* __restrict__ parts, size_t psz,
                  const float* __restrict__ rowsum,
                  bf* __restrict__ out, int n)
{
    int i = (blockIdx.x * 256 + threadIdx.x) * 8;
    if (i + 8 > n) return;
    const float inv = 1.0f / rowsum[i >> 10];   // D_DIM = 1024 elems/row
    float s[8] = {};
#pragma unroll
    for (int z = 0; z < KSPLIT; ++z) {
        union { int4 v; bf h[8]; } u;
        u.v = *(const int4*)(parts + z * psz + i);
#pragma unroll
        for (int e = 0; e < 8; ++e) s[e] += __bfloat162float(u.h[e]);
    }
    union { int4 v; bf h[8]; } o;
#pragma unroll
    for (int e = 0; e < 8; ++e) o.h[e] = __float2bfloat16(s[e] * inv);
    *(int4*)(out + i) = o.v;
}

// dual row L2-normalize -> bf16: out[r] = bf16(Gs[r]/||Gs[r]|| + Gt[r]/||Gt[r]||)
__global__ __launch_bounds__(256)
void rownorm2(const float* __restrict__ G, bf* __restrict__ out)
{
    __shared__ float red[16];
    const int tid = threadIdx.x;
    const float* ps = G + (size_t)blockIdx.x * D_DIM;
    const float* pt = ps + (size_t)B_ROWS * D_DIM;
    float4 a = *(const float4*)(ps + tid * 4);
    float4 b = *(const float4*)(pt + tid * 4);
    float sa = a.x * a.x + a.y * a.y + a.z * a.z + a.w * a.w;
    float sb = b.x * b.x + b.y * b.y + b.z * b.z + b.w * b.w;
    for (int s = 32; s > 0; s >>= 1) {
        sa += __shfl_down(sa, s, 64);
        sb += __shfl_down(sb, s, 64);
    }
    if ((tid & 63) == 0) { red[tid >> 6] = sa; red[8 + (tid >> 6)] = sb; }
    __syncthreads();
    if (tid == 0) {
        float ta = 0.f, tb = 0.f;
        for (int w = 0; w < 4; ++w) { ta += red[w]; tb += red[8 + w]; }
        red[4] = rsqrtf(ta); red[12] = rsqrtf(tb);
    }
    __syncthreads();
    const float ia = red[4], ib = red[12];
    union { bf h[4]; int2 v; } u;
    u.h[0] = __float2bfloat16(a.x * ia + b.x * ib);
    u.h[1] = __float2bfloat16(a.y * ia + b.y * ib);
    u.h[2] = __float2bfloat16(a.z * ia + b.z * ib);
    u.h[3] = __float2bfloat16(a.w * ia + b.w * ib);
    *(int2*)(out + (size_t)blockIdx.x * D_DIM + tid * 4) = u.v;
}

// concat-convert Fv|Fvs|Fvt -> Xb (bf16), 8/thread
__global__ __launch_bounds__(256)
void convX(const float* __restrict__ Fv, const float* __restrict__ Fvs,
           const float* __restrict__ Fvt, bf* __restrict__ X)
{
    int i = (blockIdx.x * 256 + threadIdx.x) * 8;
    const int n0 = B_ROWS * D_DIM, n1 = n0 + NBANK * D_DIM;
    const float* src;
    int off;
    if (i < n0)      { src = Fv;  off = i; }
    else if (i < n1) { src = Fvs; off = i - n0; }
    else             { src = Fvt; off = i - n1; }
    float4 a = *(const float4*)(src + off);
    float4 b = *(const float4*)(src + off + 4);
    union { bf h[8]; int4 v; } u;
    u.h[0] = __float2bfloat16(a.x); u.h[1] = __float2bfloat16(a.y);
    u.h[2] = __float2bfloat16(a.z); u.h[3] = __float2bfloat16(a.w);
    u.h[4] = __float2bfloat16(b.x); u.h[5] = __float2bfloat16(b.y);
    u.h[6] = __float2bfloat16(b.z); u.h[7] = __float2bfloat16(b.w);
    *(int4*)(X + i) = u.v;
}

// convert W1|W2|Wp -> bf16, 8/thread
__global__ __launch_bounds__(256)
void convW(const float* __restrict__ W1, const float* __restrict__ W2,
           const float* __restrict__ Wp,
           bf* __restrict__ W1b, bf* __restrict__ W2b, bf* __restrict__ Wpb)
{
    int i = (blockIdx.x * 256 + threadIdx.x) * 8;
    const int n1 = P_DIM * D_DIM;           // 131072
    const int n2 = n1 + P_DIM * P_DIM;      // 147456
    const int n3 = n2 + D_DIM * D_DIM;      // 1196032
    if (i >= n3) return;
    const float* src; bf* dst; int off;
    if (i < n1)      { src = W1; dst = W1b; off = i; }
    else if (i < n2) { src = W2; dst = W2b; off = i - n1; }
    else             { src = Wp; dst = Wpb; off = i - n2; }
    float4 a = *(const float4*)(src + off);
    float4 b = *(const float4*)(src + off + 4);
    union { bf h[8]; int4 v; } u;
    u.h[0] = __float2bfloat16(a.x); u.h[1] = __float2bfloat16(a.y);
    u.h[2] = __float2bfloat16(a.z); u.h[3] = __float2bfloat16(a.w);
    u.h[4] = __float2bfloat16(b.x); u.h[5] = __float2bfloat16(b.y);
    u.h[6] = __float2bfloat16(b.z); u.h[7] = __float2bfloat16(b.w);
    *(int4*)(dst + off) = u.v;
}

// pack W3 (3072x128 fp32) into W3q/W3k/W3v (1024x128 bf16, rows 3d+rr) + b3 split
__global__ __launch_bounds__(256)
void convW3(const float* __restrict__ W3, const float* __restrict__ b3,
            bf* __restrict__ W3q, bf* __restrict__ W3k, bf* __restrict__ W3v,
            float* __restrict__ b3q, float* __restrict__ b3k, float* __restrict__ b3v)
{
    int gid = blockIdx.x * 256 + threadIdx.x;
    int i = gid * 8;
    if (i < D_DIM * P_DIM) {
        int d = i >> 7, p = i & 127;
#pragma unroll
        for (int rr = 0; rr < 3; ++rr) {
            const float* src = W3 + (size_t)(3 * d + rr) * P_DIM + p;
            bf* dst = (rr == 0 ? W3q : rr == 1 ? W3k : W3v) + i;
            float4 a = *(const float4*)src;
            float4 b = *(const float4*)(src + 4);
            union { bf h[8]; int4 v; } u;
            u.h[0] = __float2bfloat16(a.x); u.h[1] = __float2bfloat16(a.y);
            u.h[2] = __float2bfloat16(a.z); u.h[3] = __float2bfloat16(a.w);
            u.h[4] = __float2bfloat16(b.x); u.h[5] = __float2bfloat16(b.y);
            u.h[6] = __float2bfloat16(b.z); u.h[7] = __float2bfloat16(b.w);
            *(int4*)dst = u.v;
        }
    }
    if (gid < D_DIM) {
        b3q[gid] = b3[3 * gid];
        b3k[gid] = b3[3 * gid + 1];
        b3v[gid] = b3[3 * gid + 2];
    }
}

// Ft [1000,1024] fp32 -> [1024,1024] bf16, rows 1000..1023 zero
__global__ __launch_bounds__(256)
void ftpad(const float* __restrict__ Ft, bf* __restrict__ out)
{
    int idx = blockIdx.x * 256 + threadIdx.x;
    int row = idx >> 10, col = idx & 1023;
    float v = (row < C_CLS) ? Ft[(size_t)row * D_DIM + col] : 0.f;
    out[idx] = __float2bfloat16(v);
}

extern "C" void kernel_launch(void* const* d_in, const int* in_sizes, int n_in,
                              void* d_out, int out_size, void* d_ws, size_t ws_size,
                              hipStream_t stream)
{
    (void)in_sizes; (void)n_in; (void)out_size; (void)ws_size;

    const float* Ft  = (const float*)d_in[0];
    const float* Fv  = (const float*)d_in[1];
    const float* Fvs = (const float*)d_in[2];
    const float* Fvt = (const float*)d_in[3];
    const float* W1  = (const float*)d_in[4];
    const float* b1  = (const float*)d_in[5];
    const float* g1  = (const float*)d_in[6];
    const float* be1 = (const float*)d_in[7];
    const float* m1  = (const float*)d_in[8];
    const float* v1  = (const float*)d_in[9];
    const float* W2  = (const float*)d_in[10];
    const float* b2  = (const float*)d_in[11];
    const float* g2  = (const float*)d_in[12];
    const float* be2 = (const float*)d_in[13];
    const float* m2  = (const float*)d_in[14];
    const float* v2  = (const float*)d_in[15];
    const float* W3  = (const float*)d_in[16];
    const float* b3  = (const float*)d_in[17];
    const float* Wp  = (const float*)d_in[18];
    const float* bp  = (const float*)d_in[19];
    const float* ls  = (const float*)d_in[20];

    char* base = (char*)d_ws;
    size_t o = 0;
    auto take = [&](size_t s) { size_t r = o; o += (s + 255) & ~(size_t)255; return r; };

    // persistent (~94 MB)
    bf* qb    = (bf*)(base + take((size_t)B_ROWS * D_DIM * 2));
    bf* kall  = (bf*)(base + take((size_t)2 * NBANK * D_DIM * 2));   // [16384,1024]
    bf* vTall = (bf*)(base + take((size_t)D_DIM * 2 * NBANK * 2));   // [1024,16384]
    bf* Yst   = (bf*)(base + take((size_t)2 * B_ROWS * D_DIM * 2));  // [Ys; Yt]
    bf* Wpb   = (bf*)(base + take((size_t)D_DIM * D_DIM * 2));
    bf* Ftb   = (bf*)(base + take((size_t)D_DIM * D_DIM * 2));
    bf* W3q   = (bf*)(base + take((size_t)D_DIM * P_DIM * 2));
    bf* W3k   = (bf*)(base + take((size_t)D_DIM * P_DIM * 2));
    bf* W3v   = (bf*)(base + take((size_t)D_DIM * P_DIM * 2));
    float* b3q = (float*)(base + take(D_DIM * 4));
    float* b3k = (float*)(base + take(D_DIM * 4));
    float* b3v = (float*)(base + take(D_DIM * 4));
    float* rsum = (float*)(base + take(B_ROWS * 4));
    bf* Ysb = Yst;
    bf* Ytb = Yst + (size_t)B_ROWS * D_DIM;

    // region D (aliased, 96 MB)
    size_t Dbase = o;
    size_t p = Dbase;
    auto take2 = [&](size_t s) { size_t r = p; p += (s + 255) & ~(size_t)255; return r; };
    bf* Xb  = (bf*)(base + take2((size_t)MTOT * D_DIM * 2));
    bf* h1b = (bf*)(base + take2((size_t)MTOT * P_DIM * 2));
    bf* h2b = (bf*)(base + take2((size_t)MTOT * P_DIM * 2));
    bf* W1b = (bf*)(base + take2((size_t)P_DIM * D_DIM * 2));
    bf* W2b = (bf*)(base + take2((size_t)P_DIM * P_DIM * 2));
    // P3 view
    bf* Sb    = (bf*)(base + Dbase);
    bf* Opart = (bf*)(base + Dbase + (size_t)B_ROWS * NBANK * 2);
    // P4 view
    float* G     = (float*)(base + Dbase);
    bf*    Fsumb = (bf*)(base + Dbase + (size_t)3 * B_ROWS * D_DIM * 4);

    auto gemm = [&](const bf* A, const bf* B, int M, int N, int K, int ldb,
                    int kch, int fx, int fy, int epi, float* Cf, bf* Cb,
                    const float* bias, const float* biasm,
                    const float* bg, const float* bb, const float* bm, const float* bv,
                    const float* addsrc, const float* lsp, float* rs, int ldc) {
        gemm_bf16<<<dim3(N / 128, M / 128, kch), dim3(256), 0, stream>>>(
            A, B, M, N, K, ldb, kch, fx, fy, epi, Cf, Cb, bias, biasm,
            bg, bb, bm, bv, addsrc, lsp, rs, ldc);
    };

    // P1: conversions
    convX<<<dim3(MTOT * D_DIM / 2048), dim3(256), 0, stream>>>(Fv, Fvs, Fvt, Xb);
    convW<<<dim3(584), dim3(256), 0, stream>>>(W1, W2, Wp, W1b, W2b, Wpb);
    convW3<<<dim3(64), dim3(256), 0, stream>>>(W3, b3, W3q, W3k, W3v, b3q, b3k, b3v);
    ftpad<<<dim3(D_DIM * D_DIM / 256), dim3(256), 0, stream>>>(Ft, Ftb);

    // P2: batched pre_project, then clean q/k/vT GEMMs (no scatter)
    gemm(Xb, W1b, MTOT, P_DIM, D_DIM, D_DIM, 1, 1, 8, 1, nullptr, h1b,
         b1, nullptr, g1, be1, m1, v1, nullptr, nullptr, nullptr, 0);
    gemm(h1b, W2b, MTOT, P_DIM, P_DIM, P_DIM, 1, 1, 8, 1, nullptr, h2b,
         b2, nullptr, g2, be2, m2, v2, nullptr, nullptr, nullptr, 0);
    gemm(h2b, W3q, B_ROWS, D_DIM, P_DIM, P_DIM, 1, 1, 8, 5, nullptr, qb,
         b3q, nullptr, nullptr, nullptr, nullptr, nullptr, nullptr, nullptr,
         nullptr, 0);
    gemm(h2b + (size_t)B_ROWS * P_DIM, W3k, 2 * NBANK, D_DIM, P_DIM, P_DIM, 1,
         1, 8, 5, nullptr, kall, b3k, nullptr, nullptr, nullptr, nullptr, nullptr,
         nullptr, nullptr, nullptr, 0);
    gemm(W3v, h2b + (size_t)B_ROWS * P_DIM, D_DIM, 2 * NBANK, P_DIM, P_DIM, 1,
         8, 1, 5, nullptr, vTall, nullptr, b3v, nullptr, nullptr, nullptr, nullptr,
         nullptr, nullptr, nullptr, 0);

    // P3: per side: QK^T (exp + fused atomic rowsum) -> split-K A@V -> reduce+scale
    for (int side = 0; side < 2; ++side) {
        const bf* kb = kall + (size_t)side * NBANK * D_DIM;
        const bf* vT = vTall + (size_t)side * NBANK;
        bf* Yb = side ? Ytb : Ysb;
        zerof<<<dim3(16), dim3(256), 0, stream>>>(rsum, B_ROWS);
        gemm(qb, kb, B_ROWS, NBANK, D_DIM, D_DIM, 1, 4, 2, 7, nullptr, Sb,
             nullptr, nullptr, nullptr, nullptr, nullptr, nullptr,
             nullptr, nullptr, rsum, 0);
        gemm(Sb, vT, B_ROWS, D_DIM, NBANK, 2 * NBANK, KSPLIT, 1, 8, 6,
             nullptr, Opart, nullptr, nullptr, nullptr, nullptr, nullptr, nullptr,
             nullptr, nullptr, nullptr, 0);
        reduce_parts<<<dim3(B_ROWS * D_DIM / 2048), dim3(256), 0, stream>>>(
            Opart, (size_t)B_ROWS * D_DIM, rsum, Yb, B_ROWS * D_DIM);
    }

    // P4: combined post-project (M=8192) + dual rownorm (-> bf16) + logits
    gemm(Yst, Wpb, 2 * B_ROWS, D_DIM, D_DIM, D_DIM, 1, 1, 8, 3, G, nullptr,
         bp, nullptr, nullptr, nullptr, nullptr, nullptr, Fv, nullptr, nullptr, B_ROWS);
    rownorm2<<<dim3(B_ROWS), dim3(256), 0, stream>>>(G, Fsumb);
    gemm(Fsumb, Ftb, B_ROWS, D_DIM, D_DIM, D_DIM, 1, 1, 8, 4, (float*)d_out, nullptr,
         nullptr, nullptr, nullptr, nullptr, nullptr, nullptr, nullptr, ls, nullptr, C_CLS);
}